// Round 4
// baseline (440.904 us; speedup 1.0000x reference)
//
#include <hip/hip_runtime.h>

#define B_ROWS 1024
#define D_DIM  512
#define C_CLS  100000
#define N_TILES 782     // ceil(100000/128)
#define GRID_NJ 98      // 98*8 = 784 >= 782 (XCD-swizzle padding, 16 idle blocks)

typedef unsigned short u16;
typedef __attribute__((ext_vector_type(8))) short bf16x8;
typedef __attribute__((ext_vector_type(4))) float f32x4;

__device__ __forceinline__ u16 f2bf(float f) {
  unsigned u = __float_as_uint(f);
  u += 0x7fffu + ((u >> 16) & 1u);   // round-to-nearest-even
  return (u16)(u >> 16);
}

// pack 8 fp32 -> 8 bf16 (RTZ high-16) via v_perm_b32 (fallback path only)
__device__ __forceinline__ bf16x8 pack8(float4 a, float4 b) {
  union { bf16x8 v; unsigned u[4]; } r;
  r.u[0] = __builtin_amdgcn_perm(__float_as_uint(a.y), __float_as_uint(a.x), 0x07060302u);
  r.u[1] = __builtin_amdgcn_perm(__float_as_uint(a.w), __float_as_uint(a.z), 0x07060302u);
  r.u[2] = __builtin_amdgcn_perm(__float_as_uint(b.y), __float_as_uint(b.x), 0x07060302u);
  r.u[3] = __builtin_amdgcn_perm(__float_as_uint(b.w), __float_as_uint(b.z), 0x07060302u);
  return r.v;
}

__device__ __forceinline__ void gll16(const void* g, void* l) {
  __builtin_amdgcn_global_load_lds(
      (const __attribute__((address_space(1))) unsigned int*)g,
      (__attribute__((address_space(3))) unsigned int*)l, 16, 0, 0);
}

// ---------------- fast path: prep (features + weights -> normalized bf16) ---
// Grid-stride, TWO rows per wave iteration: both rows' 4 KB of loads issue
// before either reduce chain starts (2x memory-level parallelism vs 1-row).
// L2-normalize in fp32, emit bf16 (RNE) -> MFMA output is cosine directly.
__global__ __launch_bounds__(256) void prep_kernel(
    const float* __restrict__ feat, const float* __restrict__ wt,
    u16* __restrict__ fn, u16* __restrict__ wb, float* __restrict__ psum)
{
  const int lane  = threadIdx.x & 63;
  const int wid   = blockIdx.x * 4 + (threadIdx.x >> 6);
  const int nw    = gridDim.x * 4;          // 8192 waves
  const int total = B_ROWS + C_CLS;
  for (int row = wid; row < total; row += 2 * nw) {
    const int rowb  = row + nw;
    const bool hasb = rowb < total;
    const float* sa = (row < B_ROWS) ? feat + (size_t)row * D_DIM
                                     : wt + (size_t)(row - B_ROWS) * D_DIM;
    u16* da = (row < B_ROWS) ? fn + (size_t)row * D_DIM
                             : wb + (size_t)(row - B_ROWS) * D_DIM;
    const float* sb = sa;
    u16* db = da;
    if (hasb) {   // nw > B_ROWS so rowb is always a weight row, but stay general
      sb = (rowb < B_ROWS) ? feat + (size_t)rowb * D_DIM
                           : wt + (size_t)(rowb - B_ROWS) * D_DIM;
      db = (rowb < B_ROWS) ? fn + (size_t)rowb * D_DIM
                           : wb + (size_t)(rowb - B_ROWS) * D_DIM;
    }
    const float4 a0 = ((const float4*)sa)[lane];
    const float4 a1 = ((const float4*)sa)[lane + 64];
    const float4 b0 = ((const float4*)sb)[lane];
    const float4 b1 = ((const float4*)sb)[lane + 64];
    float ssa = a0.x*a0.x + a0.y*a0.y + a0.z*a0.z + a0.w*a0.w
              + a1.x*a1.x + a1.y*a1.y + a1.z*a1.z + a1.w*a1.w;
    float ssb = b0.x*b0.x + b0.y*b0.y + b0.z*b0.z + b0.w*b0.w
              + b1.x*b1.x + b1.y*b1.y + b1.z*b1.z + b1.w*b1.w;
#pragma unroll
    for (int m = 1; m < 64; m <<= 1) {      // two independent chains interleave
      ssa += __shfl_xor(ssa, m);
      ssb += __shfl_xor(ssb, m);
    }
    const float inva = 1.0f / fmaxf(sqrtf(ssa), 1e-12f);
    const float invb = 1.0f / fmaxf(sqrtf(ssb), 1e-12f);
    ushort4 oa0, oa1, ob0, ob1;
    oa0.x = f2bf(a0.x * inva); oa0.y = f2bf(a0.y * inva);
    oa0.z = f2bf(a0.z * inva); oa0.w = f2bf(a0.w * inva);
    oa1.x = f2bf(a1.x * inva); oa1.y = f2bf(a1.y * inva);
    oa1.z = f2bf(a1.z * inva); oa1.w = f2bf(a1.w * inva);
    ((ushort4*)da)[lane]      = oa0;
    ((ushort4*)da)[lane + 64] = oa1;
    if (hasb) {
      ob0.x = f2bf(b0.x * invb); ob0.y = f2bf(b0.y * invb);
      ob0.z = f2bf(b0.z * invb); ob0.w = f2bf(b0.w * invb);
      ob1.x = f2bf(b1.x * invb); ob1.y = f2bf(b1.y * invb);
      ob1.z = f2bf(b1.z * invb); ob1.w = f2bf(b1.w * invb);
      ((ushort4*)db)[lane]      = ob0;
      ((ushort4*)db)[lane + 64] = ob1;
    }
    if (row < B_ROWS && lane == 0) psum[row] = 0.0f;
  }
}

// ---------------- fast path: 128x128 / BK=32 double-buffered 2-phase GEMM ---
// T3 minimum 2-phase recipe: issue next K-tile's global_load_lds BEFORE
// computing the current one; the __syncthreads vmcnt(0) drain lands AFTER
// ~16 MFMA + ds_reads of compute have hidden the L2/L3 load latency.
// WAR is safe: prev iteration's barrier (+lgkmcnt0) fences all reads of the
// buffer being overwritten. BK=32 dbuf = 33 KB LDS -> keeps 4 blocks/CU.
__global__ __launch_bounds__(256, 4) void arc_gemm_pre(
    const u16* __restrict__ fn, const u16* __restrict__ wb,
    const int* __restrict__ targets, float* __restrict__ psum,
    float* __restrict__ tlogit)
{
  __shared__ u16 As[2][128 * 32];
  __shared__ u16 Ws[2][128 * 32];
  __shared__ int tg[128];
  __shared__ float pr[256];

  const int tid = threadIdx.x;
  const int bx  = blockIdx.x;
  const int xcd = bx & 7;
  const int l   = bx >> 3;
  const int tile_ni = (l >> 3) * 8 + xcd;
  if (tile_ni >= N_TILES) return;
  const int tile_m = (l & 7) << 7;
  const int tile_n = tile_ni << 7;

  if (tid < 128) tg[tid] = targets[tile_m + tid];

  const int wave = tid >> 6, lane = tid & 63;
  const int wm = wave >> 1, wno = wave & 1;
  const int quad = lane >> 4, l15 = lane & 15;

  f32x4 acc[4][4] = {};

  // Staging thread t owns rows (t>>2, t>>2+64) and XOR-swizzled k-chunk:
  // LDS slot (row, s) holds global chunk s ^ ((row>>1)&3) -> conflict-free
  // (proven: SQ_LDS_BANK_CONFLICT = 0). gll16 dest stays linear; swizzle is
  // applied on the per-lane GLOBAL source address (m173 pattern).
  const int srow   = tid >> 2;
  const int schunk = (tid & 3) ^ ((tid >> 3) & 3);
  const u16* Ag  = fn + (size_t)(tile_m + srow) * D_DIM + schunk * 8;
  const u16* Ag2 = Ag + 64 * D_DIM;
  const int wr0 = tile_n + srow;
  const int wr1 = wr0 + 64;
  // clamp pad rows (tile 781 extends past 100000); masked in epilogue anyway
  const u16* Wg0 = wb + (size_t)min(wr0, C_CLS - 1) * D_DIM + schunk * 8;
  const u16* Wg1 = wb + (size_t)min(wr1, C_CLS - 1) * D_DIM + schunk * 8;

  // read-side swizzle: (row>>1)&3 == (l15>>1)&3 (r*16, wm*64 are 0 mod 8)
  const int rsw = (quad ^ ((l15 >> 1) & 3)) * 8;
  const u16* ApA = &As[0][(wm * 64 + l15) * 32 + rsw];
  const u16* ApW = &Ws[0][(wno * 64 + l15) * 32 + rsw];

  auto stage = [&](int b, int k0) {
    gll16(Ag  + k0, &As[b][tid * 8]);
    gll16(Ag2 + k0, &As[b][2048 + tid * 8]);
    gll16(Wg0 + k0, &Ws[b][tid * 8]);
    gll16(Wg1 + k0, &Ws[b][2048 + tid * 8]);
  };
  auto compute = [&](int b) {
    const u16* pA = ApA + b * 4096;   // buffer stride = 128*32 u16
    const u16* pW = ApW + b * 4096;
    bf16x8 af[4], wf[4];
#pragma unroll
    for (int r = 0; r < 4; r++) af[r] = *(const bf16x8*)(pA + r * 512);
#pragma unroll
    for (int r = 0; r < 4; r++) wf[r] = *(const bf16x8*)(pW + r * 512);
#pragma unroll
    for (int rm = 0; rm < 4; rm++)
#pragma unroll
      for (int rn = 0; rn < 4; rn++)
        acc[rm][rn] = __builtin_amdgcn_mfma_f32_16x16x32_bf16(
            af[rm], wf[rn], acc[rm][rn], 0, 0, 0);
  };

  // prologue: fill buffer 0
  stage(0, 0);
  __syncthreads();                    // vmcnt(0): buf0 ready
  int cur = 0;
  for (int k0 = 32; k0 < D_DIM; k0 += 32) {
    stage(cur ^ 1, k0);               // issue next tile FIRST (overlap)
    compute(cur);                     // ds_read + 16 MFMA hide load latency
    __syncthreads();                  // vmcnt(0)+lgkmcnt(0)+barrier: RAW+WAR
    cur ^= 1;
  }
  compute(cur);                       // epilogue tile (no prefetch)

  const float Sc   = 30.0f;
  const float COSM = 0.9553364891256060f;
  const float SINM = 0.2955202066613396f;
  const float THc  = -0.9553364891256060f;
  const float MMc  = 0.0886560619984019f;

#pragma unroll
  for (int rm = 0; rm < 4; rm++) {
#pragma unroll
    for (int reg = 0; reg < 4; reg++) {
      const int bl = wm * 64 + rm * 16 + quad * 4 + reg;  // C/D row = M index
      const int b = tile_m + bl;
      const int tgt = tg[bl];
      float s = 0.0f;
#pragma unroll
      for (int rn = 0; rn < 4; rn++) {
        const int c = tile_n + wno * 64 + rn * 16 + l15;  // C/D col = N index
        const float cosv = acc[rm][rn][reg];              // already cosine
        float logit = Sc * cosv;
        if (c == tgt) {
          const float sine = sqrtf(fmaxf(1.0f - cosv * cosv, 0.0f));
          float phi = cosv * COSM - sine * SINM;
          phi = (cosv > THc) ? phi : (cosv - MMc);
          logit = Sc * phi;
          tlogit[b] = logit;   // exactly one lane in the grid owns (b, tgt)
        }
        s += (c < C_CLS) ? __expf(logit - 30.0f) : 0.0f;  // mask pad columns
      }
      s += __shfl_xor(s, 1);
      s += __shfl_xor(s, 2);
      s += __shfl_xor(s, 4);
      s += __shfl_xor(s, 8);
      if (l15 == 0) pr[wno * 128 + bl] = s;   // stage column-half partial
    }
  }
  __syncthreads();
  // fold the two column-half waves -> one device-scope atomic per row
  if (tid < 128) atomicAdd(psum + tile_m + tid, pr[tid] + pr[128 + tid]);
}

// ---------------- fallback path (round-0 proven kernels) --------------------
__global__ void norm_feat_kernel(const float* __restrict__ in,
                                 u16* __restrict__ out,
                                 float* __restrict__ psum)
{
  const int row  = blockIdx.x * 4 + (threadIdx.x >> 6);
  const int lane = threadIdx.x & 63;
  const float4* r = (const float4*)(in + (size_t)row * D_DIM);
  float4 v0 = r[lane];
  float4 v1 = r[lane + 64];
  float ss = v0.x*v0.x + v0.y*v0.y + v0.z*v0.z + v0.w*v0.w
           + v1.x*v1.x + v1.y*v1.y + v1.z*v1.z + v1.w*v1.w;
#pragma unroll
  for (int m = 1; m < 64; m <<= 1) ss += __shfl_xor(ss, m);
  const float inv = 1.0f / fmaxf(sqrtf(ss), 1e-12f);
  ushort4 o0, o1;
  o0.x = f2bf(v0.x * inv); o0.y = f2bf(v0.y * inv);
  o0.z = f2bf(v0.z * inv); o0.w = f2bf(v0.w * inv);
  o1.x = f2bf(v1.x * inv); o1.y = f2bf(v1.y * inv);
  o1.z = f2bf(v1.z * inv); o1.w = f2bf(v1.w * inv);
  ushort4* orow = (ushort4*)(out + (size_t)row * D_DIM);
  orow[lane]      = o0;
  orow[lane + 64] = o1;
  if (lane == 0) psum[row] = 0.0f;
}

__global__ __launch_bounds__(256, 4) void arc_gemm_raw(
    const u16* __restrict__ fn, const float* __restrict__ wt,
    const int* __restrict__ targets, float* __restrict__ psum,
    float* __restrict__ tlogit)
{
  __shared__ u16 As[128 * 32];
  __shared__ u16 Ws[128 * 32];
  __shared__ int tg[128];
  __shared__ float winv[128];

  const int tid = threadIdx.x;
  const int bx  = blockIdx.x;
  const int xcd = bx & 7;
  const int l   = bx >> 3;
  const int tile_ni = (l >> 3) * 8 + xcd;
  if (tile_ni >= N_TILES) return;
  const int tile_m = (l & 7) << 7;
  const int tile_n = tile_ni << 7;

  if (tid < 128) tg[tid] = targets[tile_m + tid];

  const int wave = tid >> 6, lane = tid & 63;
  const int wm = wave >> 1, wno = wave & 1;
  const int quad = lane >> 4, l15 = lane & 15;

  f32x4 acc[4][4] = {};

  const int srow   = tid >> 2;
  const int schunk = (tid & 3) ^ ((tid >> 3) & 3);
  const u16* Ag = fn + (size_t)(tile_m + srow) * D_DIM + schunk * 8;
  u16* Asd0 = As + tid * 8;
  u16* Asd1 = As + 2048 + tid * 8;
  const int wr0 = tile_n + srow;
  const int wr1 = wr0 + 64;
  const float* Wg0 = wt + (size_t)min(wr0, C_CLS - 1) * D_DIM + schunk * 8;
  const float* Wg1 = wt + (size_t)min(wr1, C_CLS - 1) * D_DIM + schunk * 8;
  u16* Wsd0 = Ws + tid * 8;
  u16* Wsd1 = Ws + 2048 + tid * 8;

  const int rsw = (quad ^ ((l15 >> 1) & 3)) * 8;
  const u16* ApA = As + (wm * 64 + l15) * 32 + rsw;
  const u16* ApW = Ws + (wno * 64 + l15) * 32 + rsw;

  float ssq0 = 0.0f, ssq1 = 0.0f;

  for (int k0 = 0; k0 < D_DIM; k0 += 32) {
    const float4 wa = *(const float4*)(Wg0 + k0);
    const float4 wb2 = *(const float4*)(Wg0 + k0 + 4);
    const float4 wc = *(const float4*)(Wg1 + k0);
    const float4 wd = *(const float4*)(Wg1 + k0 + 4);
    gll16(Ag + k0, Asd0);
    gll16(Ag + 64 * D_DIM + k0, Asd1);
    ssq0 += wa.x*wa.x + wa.y*wa.y + wa.z*wa.z + wa.w*wa.w
          + wb2.x*wb2.x + wb2.y*wb2.y + wb2.z*wb2.z + wb2.w*wb2.w;
    ssq1 += wc.x*wc.x + wc.y*wc.y + wc.z*wc.z + wc.w*wc.w
          + wd.x*wd.x + wd.y*wd.y + wd.z*wd.z + wd.w*wd.w;
    *(bf16x8*)Wsd0 = pack8(wa, wb2);
    *(bf16x8*)Wsd1 = pack8(wc, wd);
    __syncthreads();
    bf16x8 af[4], wf[4];
#pragma unroll
    for (int r = 0; r < 4; r++) af[r] = *(const bf16x8*)(ApA + r * 16 * 32);
#pragma unroll
    for (int r = 0; r < 4; r++) wf[r] = *(const bf16x8*)(ApW + r * 16 * 32);
#pragma unroll
    for (int rm = 0; rm < 4; rm++)
#pragma unroll
      for (int rn = 0; rn < 4; rn++)
        acc[rm][rn] = __builtin_amdgcn_mfma_f32_16x16x32_bf16(
            af[rm], wf[rn], acc[rm][rn], 0, 0, 0);
    __syncthreads();
  }

  ssq0 += __shfl_xor(ssq0, 1); ssq0 += __shfl_xor(ssq0, 2);
  ssq1 += __shfl_xor(ssq1, 1); ssq1 += __shfl_xor(ssq1, 2);
  if ((tid & 3) == 0) {
    winv[srow]      = 1.0f / fmaxf(sqrtf(ssq0), 1e-12f);
    winv[srow + 64] = 1.0f / fmaxf(sqrtf(ssq1), 1e-12f);
  }
  __syncthreads();

  float wiv[4];
#pragma unroll
  for (int rn = 0; rn < 4; rn++) wiv[rn] = winv[wno * 64 + rn * 16 + l15];

  const float Sc   = 30.0f;
  const float COSM = 0.9553364891256060f;
  const float SINM = 0.2955202066613396f;
  const float THc  = -0.9553364891256060f;
  const float MMc  = 0.0886560619984019f;

#pragma unroll
  for (int rm = 0; rm < 4; rm++) {
#pragma unroll
    for (int reg = 0; reg < 4; reg++) {
      const int bl = wm * 64 + rm * 16 + quad * 4 + reg;
      const int b = tile_m + bl;
      const int tgt = tg[bl];
      float s = 0.0f;
#pragma unroll
      for (int rn = 0; rn < 4; rn++) {
        const int c = tile_n + wno * 64 + rn * 16 + l15;
        const float cosv = acc[rm][rn][reg] * wiv[rn];
        float logit = Sc * cosv;
        if (c == tgt) {
          const float sine = sqrtf(fmaxf(1.0f - cosv * cosv, 0.0f));
          float phi = cosv * COSM - sine * SINM;
          phi = (cosv > THc) ? phi : (cosv - MMc);
          logit = Sc * phi;
          tlogit[b] = logit;
        }
        s += (c < C_CLS) ? __expf(logit - 30.0f) : 0.0f;
      }
      s += __shfl_xor(s, 1);
      s += __shfl_xor(s, 2);
      s += __shfl_xor(s, 4);
      s += __shfl_xor(s, 8);
      if (l15 == 0) atomicAdd(psum + b, s);
    }
  }
}

__global__ void finalize_loss(const float* __restrict__ psum,
                              const float* __restrict__ tlogit,
                              float* __restrict__ out)
{
  const int tid = threadIdx.x;
  float s = 0.0f;
  for (int i = tid; i < B_ROWS; i += 256)
    s += 30.0f + logf(psum[i]) - tlogit[i];
#pragma unroll
  for (int m = 1; m < 64; m <<= 1) s += __shfl_xor(s, m);
  __shared__ float red[4];
  if ((tid & 63) == 0) red[tid >> 6] = s;
  __syncthreads();
  if (tid == 0) out[0] = (red[0] + red[1] + red[2] + red[3]) * (1.0f / B_ROWS);
}

extern "C" void kernel_launch(void* const* d_in, const int* in_sizes, int n_in,
                              void* d_out, int out_size, void* d_ws, size_t ws_size,
                              hipStream_t stream) {
  const float* feat = (const float*)d_in[0];
  const float* wt   = (const float*)d_in[1];
  const int*   tgt  = (const int*)d_in[2];
  float* out = (float*)d_out;
  char* ws = (char*)d_ws;

  const size_t fn_bytes = (size_t)B_ROWS * D_DIM * 2;        // 1 MB
  const size_t wb_bytes = (size_t)C_CLS * D_DIM * 2;         // 102.4 MB
  const size_t tail     = 2 * (size_t)B_ROWS * sizeof(float);

  if (ws_size >= fn_bytes + wb_bytes + tail) {
    // fast path: W pre-normalized to bf16 in workspace
    u16* fn = (u16*)ws;
    u16* wb = (u16*)(ws + fn_bytes);
    float* psum = (float*)(ws + fn_bytes + wb_bytes);
    float* tlogit = psum + B_ROWS;
    prep_kernel<<<2048, 256, 0, stream>>>(feat, wt, fn, wb, psum);
    arc_gemm_pre<<<GRID_NJ * 8 * 8, 256, 0, stream>>>(fn, wb, tgt, psum, tlogit);
    finalize_loss<<<1, 256, 0, stream>>>(psum, tlogit, out);
  } else {
    // fallback: proven round-0 path (~1 MB workspace)
    u16* fn = (u16*)ws;
    float* psum = (float*)(ws + fn_bytes);
    float* tlogit = psum + B_ROWS;
    norm_feat_kernel<<<B_ROWS / 4, 256, 0, stream>>>(feat, fn, psum);
    arc_gemm_raw<<<GRID_NJ * 8 * 8, 256, 0, stream>>>(fn, wt, tgt, psum, tlogit);
    finalize_loss<<<1, 256, 0, stream>>>(psum, tlogit, out);
  }
}

// Round 5
// 431.685 us; speedup vs baseline: 1.0214x; 1.0214x over previous
//
#include <hip/hip_runtime.h>

#define B_ROWS 1024
#define D_DIM  512
#define C_CLS  100000
#define N_TILES 782     // ceil(100000/128)
#define GRID_NJ 98      // 98*8 = 784 >= 782 (XCD-swizzle padding, 16 idle blocks)

typedef unsigned short u16;
typedef __attribute__((ext_vector_type(8))) short bf16x8;
typedef __attribute__((ext_vector_type(4))) float f32x4;

__device__ __forceinline__ u16 f2bf(float f) {
  unsigned u = __float_as_uint(f);
  u += 0x7fffu + ((u >> 16) & 1u);   // round-to-nearest-even
  return (u16)(u >> 16);
}

// pack 8 fp32 -> 8 bf16 (RTZ high-16) via v_perm_b32 (fallback path only)
__device__ __forceinline__ bf16x8 pack8(float4 a, float4 b) {
  union { bf16x8 v; unsigned u[4]; } r;
  r.u[0] = __builtin_amdgcn_perm(__float_as_uint(a.y), __float_as_uint(a.x), 0x07060302u);
  r.u[1] = __builtin_amdgcn_perm(__float_as_uint(a.w), __float_as_uint(a.z), 0x07060302u);
  r.u[2] = __builtin_amdgcn_perm(__float_as_uint(b.y), __float_as_uint(b.x), 0x07060302u);
  r.u[3] = __builtin_amdgcn_perm(__float_as_uint(b.w), __float_as_uint(b.z), 0x07060302u);
  return r.v;
}

__device__ __forceinline__ void gll16(const void* g, void* l) {
  __builtin_amdgcn_global_load_lds(
      (const __attribute__((address_space(1))) unsigned int*)g,
      (__attribute__((address_space(3))) unsigned int*)l, 16, 0, 0);
}

// ---------------- fast path: prep (features + weights -> normalized bf16) ---
// Lane l owns floats [8l, 8l+8) of the row: two float4 loads + ONE 16B short8
// store -> 1 KB/instruction wave-wide on both load and store sides.
// Two rows per iteration for 2x memory-level parallelism.
__global__ __launch_bounds__(256) void prep_kernel(
    const float* __restrict__ feat, const float* __restrict__ wt,
    u16* __restrict__ fn, u16* __restrict__ wb, float* __restrict__ psum)
{
  const int lane  = threadIdx.x & 63;
  const int wid   = blockIdx.x * 4 + (threadIdx.x >> 6);
  const int nw    = gridDim.x * 4;          // 8192 waves
  const int total = B_ROWS + C_CLS;
  for (int row = wid; row < total; row += 2 * nw) {
    const int rowb  = row + nw;
    const bool hasb = rowb < total;
    const float* sa = (row < B_ROWS) ? feat + (size_t)row * D_DIM
                                     : wt + (size_t)(row - B_ROWS) * D_DIM;
    u16* da = (row < B_ROWS) ? fn + (size_t)row * D_DIM
                             : wb + (size_t)(row - B_ROWS) * D_DIM;
    const float* sb = sa;
    u16* db = da;
    if (hasb) {
      sb = (rowb < B_ROWS) ? feat + (size_t)rowb * D_DIM
                           : wt + (size_t)(rowb - B_ROWS) * D_DIM;
      db = (rowb < B_ROWS) ? fn + (size_t)rowb * D_DIM
                           : wb + (size_t)(rowb - B_ROWS) * D_DIM;
    }
    const float4 a0 = ((const float4*)sa)[2 * lane];
    const float4 a1 = ((const float4*)sa)[2 * lane + 1];
    const float4 b0 = ((const float4*)sb)[2 * lane];
    const float4 b1 = ((const float4*)sb)[2 * lane + 1];
    float ssa = a0.x*a0.x + a0.y*a0.y + a0.z*a0.z + a0.w*a0.w
              + a1.x*a1.x + a1.y*a1.y + a1.z*a1.z + a1.w*a1.w;
    float ssb = b0.x*b0.x + b0.y*b0.y + b0.z*b0.z + b0.w*b0.w
              + b1.x*b1.x + b1.y*b1.y + b1.z*b1.z + b1.w*b1.w;
#pragma unroll
    for (int m = 1; m < 64; m <<= 1) {      // two independent chains interleave
      ssa += __shfl_xor(ssa, m);
      ssb += __shfl_xor(ssb, m);
    }
    const float inva = 1.0f / fmaxf(sqrtf(ssa), 1e-12f);
    const float invb = 1.0f / fmaxf(sqrtf(ssb), 1e-12f);
    union { bf16x8 v; u16 e[8]; } oa, ob;
    oa.e[0] = f2bf(a0.x * inva); oa.e[1] = f2bf(a0.y * inva);
    oa.e[2] = f2bf(a0.z * inva); oa.e[3] = f2bf(a0.w * inva);
    oa.e[4] = f2bf(a1.x * inva); oa.e[5] = f2bf(a1.y * inva);
    oa.e[6] = f2bf(a1.z * inva); oa.e[7] = f2bf(a1.w * inva);
    ((bf16x8*)da)[lane] = oa.v;             // 16B store, row fully contiguous
    if (hasb) {
      ob.e[0] = f2bf(b0.x * invb); ob.e[1] = f2bf(b0.y * invb);
      ob.e[2] = f2bf(b0.z * invb); ob.e[3] = f2bf(b0.w * invb);
      ob.e[4] = f2bf(b1.x * invb); ob.e[5] = f2bf(b1.y * invb);
      ob.e[6] = f2bf(b1.z * invb); ob.e[7] = f2bf(b1.w * invb);
      ((bf16x8*)db)[lane] = ob.v;
    }
    if (row < B_ROWS && lane == 0) psum[row] = 0.0f;
  }
}

// ---------------- fast path: 128x128 / BK=32, 2-deep counted-vmcnt pipeline -
// T4 recipe: raw s_barrier + inline-asm s_waitcnt vmcnt(4). Each stage = 4
// global_load_lds/thread; steady state keeps 8 in flight (tiles t, t+1).
// vmcnt(4) waits ONLY for tile t, whose loads were issued two compute phases
// (~400+ cy) earlier -> L2/L3 latency hidden. WAR fenced by the post-compute
// barrier (ds_read results consumed by MFMAs before it). __syncthreads is NOT
// used in the K-loop: its vmcnt(0) drain would wait for the prefetch too
// (the R4 regression).
__global__ __launch_bounds__(256, 4) void arc_gemm_pre(
    const u16* __restrict__ fn, const u16* __restrict__ wb,
    const int* __restrict__ targets, float* __restrict__ psum,
    float* __restrict__ tlogit)
{
  __shared__ u16 As[2][128 * 32];
  __shared__ u16 Ws[2][128 * 32];
  __shared__ int tg[128];
  __shared__ float pr[256];

  const int tid = threadIdx.x;
  const int bx  = blockIdx.x;
  const int xcd = bx & 7;
  const int l   = bx >> 3;
  const int tile_ni = (l >> 3) * 8 + xcd;
  if (tile_ni >= N_TILES) return;          // block-uniform: no barrier mismatch
  const int tile_m = (l & 7) << 7;
  const int tile_n = tile_ni << 7;

  if (tid < 128) tg[tid] = targets[tile_m + tid];

  const int wave = tid >> 6, lane = tid & 63;
  const int wm = wave >> 1, wno = wave & 1;
  const int quad = lane >> 4, l15 = lane & 15;

  f32x4 acc[4][4] = {};

  // Staging thread t owns rows (t>>2, t>>2+64) and XOR-swizzled k-chunk:
  // LDS slot (row, s) holds global chunk s ^ ((row>>1)&3) -> conflict-free
  // (proven: SQ_LDS_BANK_CONFLICT = 0). gll16 dest stays linear; swizzle is
  // applied on the per-lane GLOBAL source address (m173 pattern).
  const int srow   = tid >> 2;
  const int schunk = (tid & 3) ^ ((tid >> 3) & 3);
  const u16* Ag  = fn + (size_t)(tile_m + srow) * D_DIM + schunk * 8;
  const u16* Ag2 = Ag + 64 * D_DIM;
  const int wr0 = tile_n + srow;
  const int wr1 = wr0 + 64;
  // clamp pad rows (tile 781 extends past 100000); masked in epilogue anyway
  const u16* Wg0 = wb + (size_t)min(wr0, C_CLS - 1) * D_DIM + schunk * 8;
  const u16* Wg1 = wb + (size_t)min(wr1, C_CLS - 1) * D_DIM + schunk * 8;

  // read-side swizzle: (row>>1)&3 == (l15>>1)&3 (r*16, wm*64 are 0 mod 8)
  const int rsw = (quad ^ ((l15 >> 1) & 3)) * 8;
  const u16* ApA = &As[0][(wm * 64 + l15) * 32 + rsw];
  const u16* ApW = &Ws[0][(wno * 64 + l15) * 32 + rsw];

  auto stage = [&](int b, int k0) {
    gll16(Ag  + k0, &As[b][tid * 8]);
    gll16(Ag2 + k0, &As[b][2048 + tid * 8]);
    gll16(Wg0 + k0, &Ws[b][tid * 8]);
    gll16(Wg1 + k0, &Ws[b][2048 + tid * 8]);
  };
  auto compute = [&](int b) {
    const u16* pA = ApA + b * 4096;   // buffer stride = 128*32 u16
    const u16* pW = ApW + b * 4096;
    bf16x8 af[4], wf[4];
#pragma unroll
    for (int r = 0; r < 4; r++) af[r] = *(const bf16x8*)(pA + r * 512);
#pragma unroll
    for (int r = 0; r < 4; r++) wf[r] = *(const bf16x8*)(pW + r * 512);
#pragma unroll
    for (int rm = 0; rm < 4; rm++)
#pragma unroll
      for (int rn = 0; rn < 4; rn++)
        acc[rm][rn] = __builtin_amdgcn_mfma_f32_16x16x32_bf16(
            af[rm], wf[rn], acc[rm][rn], 0, 0, 0);
  };

  // prologue: two tiles in flight (8 loads/thread)
  stage(0, 0);
  stage(1, 32);
  int cur = 0;
  for (int t = 0; t < 14; t++) {
    asm volatile("s_waitcnt vmcnt(4)" : : : "memory");  // tile t landed (mine)
    __builtin_amdgcn_s_barrier();                       // ...and everyone's
    asm volatile("" : : : "memory");                    // no LDS read hoisted
    compute(cur);                                       // lgkm waits: compiler
    __builtin_amdgcn_s_barrier();                       // all done reading buf
    asm volatile("" : : : "memory");
    stage(cur, (t + 2) * 32);                           // refill same buffer
    cur ^= 1;
  }
  // t = 14: tile 14 in buf cur; tile 15's 4 loads still in flight
  asm volatile("s_waitcnt vmcnt(4)" : : : "memory");
  __builtin_amdgcn_s_barrier();
  asm volatile("" : : : "memory");
  compute(cur);
  // t = 15: drain the last 4 loads
  asm volatile("s_waitcnt vmcnt(0)" : : : "memory");
  __builtin_amdgcn_s_barrier();
  asm volatile("" : : : "memory");
  compute(cur ^ 1);

  const float Sc   = 30.0f;
  const float COSM = 0.9553364891256060f;
  const float SINM = 0.2955202066613396f;
  const float THc  = -0.9553364891256060f;
  const float MMc  = 0.0886560619984019f;

#pragma unroll
  for (int rm = 0; rm < 4; rm++) {
#pragma unroll
    for (int reg = 0; reg < 4; reg++) {
      const int bl = wm * 64 + rm * 16 + quad * 4 + reg;  // C/D row = M index
      const int b = tile_m + bl;
      const int tgt = tg[bl];
      float s = 0.0f;
#pragma unroll
      for (int rn = 0; rn < 4; rn++) {
        const int c = tile_n + wno * 64 + rn * 16 + l15;  // C/D col = N index
        const float cosv = acc[rm][rn][reg];              // already cosine
        float logit = Sc * cosv;
        if (c == tgt) {
          const float sine = sqrtf(fmaxf(1.0f - cosv * cosv, 0.0f));
          float phi = cosv * COSM - sine * SINM;
          phi = (cosv > THc) ? phi : (cosv - MMc);
          logit = Sc * phi;
          tlogit[b] = logit;   // exactly one lane in the grid owns (b, tgt)
        }
        s += (c < C_CLS) ? __expf(logit - 30.0f) : 0.0f;  // mask pad columns
      }
      s += __shfl_xor(s, 1);
      s += __shfl_xor(s, 2);
      s += __shfl_xor(s, 4);
      s += __shfl_xor(s, 8);
      if (l15 == 0) pr[wno * 128 + bl] = s;   // stage column-half partial
    }
  }
  __syncthreads();
  // fold the two column-half waves -> one device-scope atomic per row
  if (tid < 128) atomicAdd(psum + tile_m + tid, pr[tid] + pr[128 + tid]);
}

// ---------------- fallback path (round-0 proven kernels) --------------------
__global__ void norm_feat_kernel(const float* __restrict__ in,
                                 u16* __restrict__ out,
                                 float* __restrict__ psum)
{
  const int row  = blockIdx.x * 4 + (threadIdx.x >> 6);
  const int lane = threadIdx.x & 63;
  const float4* r = (const float4*)(in + (size_t)row * D_DIM);
  float4 v0 = r[lane];
  float4 v1 = r[lane + 64];
  float ss = v0.x*v0.x + v0.y*v0.y + v0.z*v0.z + v0.w*v0.w
           + v1.x*v1.x + v1.y*v1.y + v1.z*v1.z + v1.w*v1.w;
#pragma unroll
  for (int m = 1; m < 64; m <<= 1) ss += __shfl_xor(ss, m);
  const float inv = 1.0f / fmaxf(sqrtf(ss), 1e-12f);
  ushort4 o0, o1;
  o0.x = f2bf(v0.x * inv); o0.y = f2bf(v0.y * inv);
  o0.z = f2bf(v0.z * inv); o0.w = f2bf(v0.w * inv);
  o1.x = f2bf(v1.x * inv); o1.y = f2bf(v1.y * inv);
  o1.z = f2bf(v1.z * inv); o1.w = f2bf(v1.w * inv);
  ushort4* orow = (ushort4*)(out + (size_t)row * D_DIM);
  orow[lane]      = o0;
  orow[lane + 64] = o1;
  if (lane == 0) psum[row] = 0.0f;
}

__global__ __launch_bounds__(256, 4) void arc_gemm_raw(
    const u16* __restrict__ fn, const float* __restrict__ wt,
    const int* __restrict__ targets, float* __restrict__ psum,
    float* __restrict__ tlogit)
{
  __shared__ u16 As[128 * 32];
  __shared__ u16 Ws[128 * 32];
  __shared__ int tg[128];
  __shared__ float winv[128];

  const int tid = threadIdx.x;
  const int bx  = blockIdx.x;
  const int xcd = bx & 7;
  const int l   = bx >> 3;
  const int tile_ni = (l >> 3) * 8 + xcd;
  if (tile_ni >= N_TILES) return;
  const int tile_m = (l & 7) << 7;
  const int tile_n = tile_ni << 7;

  if (tid < 128) tg[tid] = targets[tile_m + tid];

  const int wave = tid >> 6, lane = tid & 63;
  const int wm = wave >> 1, wno = wave & 1;
  const int quad = lane >> 4, l15 = lane & 15;

  f32x4 acc[4][4] = {};

  const int srow   = tid >> 2;
  const int schunk = (tid & 3) ^ ((tid >> 3) & 3);
  const u16* Ag = fn + (size_t)(tile_m + srow) * D_DIM + schunk * 8;
  u16* Asd0 = As + tid * 8;
  u16* Asd1 = As + 2048 + tid * 8;
  const int wr0 = tile_n + srow;
  const int wr1 = wr0 + 64;
  const float* Wg0 = wt + (size_t)min(wr0, C_CLS - 1) * D_DIM + schunk * 8;
  const float* Wg1 = wt + (size_t)min(wr1, C_CLS - 1) * D_DIM + schunk * 8;
  u16* Wsd0 = Ws + tid * 8;
  u16* Wsd1 = Ws + 2048 + tid * 8;

  const int rsw = (quad ^ ((l15 >> 1) & 3)) * 8;
  const u16* ApA = As + (wm * 64 + l15) * 32 + rsw;
  const u16* ApW = Ws + (wno * 64 + l15) * 32 + rsw;

  float ssq0 = 0.0f, ssq1 = 0.0f;

  for (int k0 = 0; k0 < D_DIM; k0 += 32) {
    const float4 wa = *(const float4*)(Wg0 + k0);
    const float4 wb2 = *(const float4*)(Wg0 + k0 + 4);
    const float4 wc = *(const float4*)(Wg1 + k0);
    const float4 wd = *(const float4*)(Wg1 + k0 + 4);
    gll16(Ag + k0, Asd0);
    gll16(Ag + 64 * D_DIM + k0, Asd1);
    ssq0 += wa.x*wa.x + wa.y*wa.y + wa.z*wa.z + wa.w*wa.w
          + wb2.x*wb2.x + wb2.y*wb2.y + wb2.z*wb2.z + wb2.w*wb2.w;
    ssq1 += wc.x*wc.x + wc.y*wc.y + wc.z*wc.z + wc.w*wc.w
          + wd.x*wd.x + wd.y*wd.y + wd.z*wd.z + wd.w*wd.w;
    *(bf16x8*)Wsd0 = pack8(wa, wb2);
    *(bf16x8*)Wsd1 = pack8(wc, wd);
    __syncthreads();
    bf16x8 af[4], wf[4];
#pragma unroll
    for (int r = 0; r < 4; r++) af[r] = *(const bf16x8*)(ApA + r * 16 * 32);
#pragma unroll
    for (int r = 0; r < 4; r++) wf[r] = *(const bf16x8*)(ApW + r * 16 * 32);
#pragma unroll
    for (int rm = 0; rm < 4; rm++)
#pragma unroll
      for (int rn = 0; rn < 4; rn++)
        acc[rm][rn] = __builtin_amdgcn_mfma_f32_16x16x32_bf16(
            af[rm], wf[rn], acc[rm][rn], 0, 0, 0);
    __syncthreads();
  }

  ssq0 += __shfl_xor(ssq0, 1); ssq0 += __shfl_xor(ssq0, 2);
  ssq1 += __shfl_xor(ssq1, 1); ssq1 += __shfl_xor(ssq1, 2);
  if ((tid & 3) == 0) {
    winv[srow]      = 1.0f / fmaxf(sqrtf(ssq0), 1e-12f);
    winv[srow + 64] = 1.0f / fmaxf(sqrtf(ssq1), 1e-12f);
  }
  __syncthreads();

  float wiv[4];
#pragma unroll
  for (int rn = 0; rn < 4; rn++) wiv[rn] = winv[wno * 64 + rn * 16 + l15];

  const float Sc   = 30.0f;
  const float COSM = 0.9553364891256060f;
  const float SINM = 0.2955202066613396f;
  const float THc  = -0.9553364891256060f;
  const float MMc  = 0.0886560619984019f;

#pragma unroll
  for (int rm = 0; rm < 4; rm++) {
#pragma unroll
    for (int reg = 0; reg < 4; reg++) {
      const int bl = wm * 64 + rm * 16 + quad * 4 + reg;
      const int b = tile_m + bl;
      const int tgt = tg[bl];
      float s = 0.0f;
#pragma unroll
      for (int rn = 0; rn < 4; rn++) {
        const int c = tile_n + wno * 64 + rn * 16 + l15;
        const float cosv = acc[rm][rn][reg] * wiv[rn];
        float logit = Sc * cosv;
        if (c == tgt) {
          const float sine = sqrtf(fmaxf(1.0f - cosv * cosv, 0.0f));
          float phi = cosv * COSM - sine * SINM;
          phi = (cosv > THc) ? phi : (cosv - MMc);
          logit = Sc * phi;
          tlogit[b] = logit;
        }
        s += (c < C_CLS) ? __expf(logit - 30.0f) : 0.0f;
      }
      s += __shfl_xor(s, 1);
      s += __shfl_xor(s, 2);
      s += __shfl_xor(s, 4);
      s += __shfl_xor(s, 8);
      if (l15 == 0) atomicAdd(psum + b, s);
    }
  }
}

__global__ void finalize_loss(const float* __restrict__ psum,
                              const float* __restrict__ tlogit,
                              float* __restrict__ out)
{
  const int tid = threadIdx.x;
  float s = 0.0f;
  for (int i = tid; i < B_ROWS; i += 256)
    s += 30.0f + logf(psum[i]) - tlogit[i];
#pragma unroll
  for (int m = 1; m < 64; m <<= 1) s += __shfl_xor(s, m);
  __shared__ float red[4];
  if ((tid & 63) == 0) red[tid >> 6] = s;
  __syncthreads();
  if (tid == 0) out[0] = (red[0] + red[1] + red[2] + red[3]) * (1.0f / B_ROWS);
}

extern "C" void kernel_launch(void* const* d_in, const int* in_sizes, int n_in,
                              void* d_out, int out_size, void* d_ws, size_t ws_size,
                              hipStream_t stream) {
  const float* feat = (const float*)d_in[0];
  const float* wt   = (const float*)d_in[1];
  const int*   tgt  = (const int*)d_in[2];
  float* out = (float*)d_out;
  char* ws = (char*)d_ws;

  const size_t fn_bytes = (size_t)B_ROWS * D_DIM * 2;        // 1 MB
  const size_t wb_bytes = (size_t)C_CLS * D_DIM * 2;         // 102.4 MB
  const size_t tail     = 2 * (size_t)B_ROWS * sizeof(float);

  if (ws_size >= fn_bytes + wb_bytes + tail) {
    // fast path: W pre-normalized to bf16 in workspace
    u16* fn = (u16*)ws;
    u16* wb = (u16*)(ws + fn_bytes);
    float* psum = (float*)(ws + fn_bytes + wb_bytes);
    float* tlogit = psum + B_ROWS;
    prep_kernel<<<2048, 256, 0, stream>>>(feat, wt, fn, wb, psum);
    arc_gemm_pre<<<GRID_NJ * 8 * 8, 256, 0, stream>>>(fn, wb, tgt, psum, tlogit);
    finalize_loss<<<1, 256, 0, stream>>>(psum, tlogit, out);
  } else {
    // fallback: proven round-0 path (~1 MB workspace)
    u16* fn = (u16*)ws;
    float* psum = (float*)(ws + fn_bytes);
    float* tlogit = psum + B_ROWS;
    norm_feat_kernel<<<B_ROWS / 4, 256, 0, stream>>>(feat, fn, psum);
    arc_gemm_raw<<<GRID_NJ * 8 * 8, 256, 0, stream>>>(fn, wt, tgt, psum, tlogit);
    finalize_loss<<<1, 256, 0, stream>>>(psum, tlogit, out);
  }
}